// Round 11
// baseline (232.632 us; speedup 1.0000x reference)
//
#include <hip/hip_runtime.h>
#include <hip/hip_bf16.h>
#include <math.h>

// ---------------------------------------------------------------------------
// ProteinInterfacePrediction
// B=4, L=R=512, K=16, DN=128, DE=64, HOPI=32, CNNC=32
//
// conv1 separability: P[l,r,:] = pA[l,:]+pB[r,:], conv1 linear =>
//   y1(pre-relu)[l,r,co] = u[cr(r)][b][l][co] + v[cl(l)][b][r][co]
// conv2 on the bf16 MFMA pipe (16x16x32), fused relu/conv3/sigmoid epilogue.
// GNN: lane-transposed e4-packed weights so every weight fetch is a
// coalesced float4; 16 independent he accumulators; fast closed-form tanh.
//
// ws layout (floats):
//   pl  : [4][512][32]   @ 0        (65536)
//   prb : [4][512][32]   @ 65536    (65536)
//   WA  : [3][3][32][32] @ 131072   (9216)   kx-summed conv1 w, [c][ky][ci][co]
//   WB  : [3][3][32][32] @ 140288   (9216)   ky-summed conv1 w, [c][kx][ci][co]
//   W2F : bf16[18][64][8]@ 149504   (4608 f) conv2 B-fragments, per-lane packed
//   u   : [3][4][512][32]@ 158720   (196608) plane stride 65536
//   v   : [3][4][512][32]@ 355328   (196608) plane stride 65536
//   WN4 : [32][128][4]   @ 551936   (16384)  WN4[d4][o][j] = WN[o][d4*4+j]
//   WE4 : [16][128][4]   @ 568320   (8192)   WE4[e4][o][j] = WE[o][e4*4+j]
//   WpT4: [32][64][4]    @ 576512   (8192)   WpT4[d4][s*32+po][j] = Wp[po][s*128+d4*4+j]
// ---------------------------------------------------------------------------

typedef __attribute__((ext_vector_type(8))) short short8v;   // 8 x bf16
typedef __attribute__((ext_vector_type(4))) float f32x4;

__device__ __forceinline__ unsigned pack_bf16_2(float x, float y) {
    __hip_bfloat16 hx = __float2bfloat16(x);
    __hip_bfloat16 hy = __float2bfloat16(y);
    unsigned short ux = *(unsigned short*)&hx;
    unsigned short uy = *(unsigned short*)&hy;
    return (unsigned)ux | ((unsigned)uy << 16);
}

__global__ __launch_bounds__(256) void prep_weights(
    const float* __restrict__ Wc1, const float* __restrict__ Wc2,
    const float* __restrict__ WN, const float* __restrict__ WE,
    const float* __restrict__ Wp,
    float* __restrict__ WA, float* __restrict__ WB,
    unsigned short* __restrict__ W2F,
    float* __restrict__ WN4, float* __restrict__ WE4,
    float* __restrict__ WpT4)
{
    const int t = blockIdx.x * 256 + threadIdx.x;   // 64 blocks -> 16384

    if (t < 9216) {
        // conv2 B-fragment packing: W2F[f][lane][j], f = tap*2 + half
        const int f    = t >> 9;          // 0..17
        const int lane = (t >> 3) & 63;
        const int j    = t & 7;
        const int tap  = f >> 1;
        const int h    = f & 1;
        const int co   = h * 16 + (lane & 15);
        const int ci   = (lane >> 4) * 8 + j;
        const float w  = Wc2[(co * 32 + ci) * 9 + tap];
        __hip_bfloat16 hb = __float2bfloat16(w);
        W2F[t] = *(unsigned short*)&hb;

        // conv1 separable tap-sum weights
        const int tap1 = t >> 10;         // 0..8
        const int ci1  = (t >> 5) & 31;
        const int co1  = t & 31;
        if (tap1 < 3) {
            const int k = tap1;
            const float* w1 = Wc1 + (co1 * 32 + ci1) * 9;
            float w0 = w1[k * 3 + 0], wq = w1[k * 3 + 1], w2 = w1[k * 3 + 2];
            WA[((0 * 3 + k) * 32 + ci1) * 32 + co1] = wq + w2;        // r == 0
            WA[((1 * 3 + k) * 32 + ci1) * 32 + co1] = w0 + wq + w2;   // interior
            WA[((2 * 3 + k) * 32 + ci1) * 32 + co1] = w0 + wq;        // r == 511
            float q0 = w1[0 * 3 + k], q1 = w1[1 * 3 + k], q2 = w1[2 * 3 + k];
            WB[((0 * 3 + k) * 32 + ci1) * 32 + co1] = q1 + q2;        // l == 0
            WB[((1 * 3 + k) * 32 + ci1) * 32 + co1] = q0 + q1 + q2;   // interior
            WB[((2 * 3 + k) * 32 + ci1) * 32 + co1] = q0 + q1;        // l == 511
        }
    }
    if (t < 16384) {   // WN4[d4][o][j] = WN[o][d4*4+j]
        const int d4 = t >> 9, o = (t >> 2) & 127, j = t & 3;
        WN4[t] = WN[o * 128 + d4 * 4 + j];
    }
    if (t < 8192) {    // WE4[e4][o][j] = WE[o][e4*4+j]
        const int e4 = t >> 9, o = (t >> 2) & 127, j = t & 3;
        WE4[t] = WE[o * 64 + e4 * 4 + j];
    }
    if (t < 8192) {    // WpT4[d4][s*32+po][j] = Wp[po][s*128+d4*4+j]
        const int d4 = t >> 8, c = (t >> 2) & 63, j = t & 3;
        const int s = c >> 5, po = c & 31;
        WpT4[t] = Wp[po * 256 + s * 128 + d4 * 4 + j];
    }
}

// One block per (side, b, n). 128 threads. All weight fetches coalesced f4.
__global__ __launch_bounds__(128) void gnn_proj_kernel(
    const float* __restrict__ lig_node, const float* __restrict__ lig_edge,
    const float* __restrict__ rec_node, const float* __restrict__ rec_edge,
    const float* __restrict__ WN4, const float* __restrict__ bN,
    const float* __restrict__ WE4, const float* __restrict__ bE,
    const float* __restrict__ WpT4, const float* __restrict__ bp,
    float* __restrict__ pl, float* __restrict__ prb)
{
    const int blk  = blockIdx.x;          // 0..4095
    const int side = blk >> 11;           // 0 = ligand, 1 = receptor
    const int b    = (blk >> 9) & 3;
    const int n    = blk & 511;
    const float* node = (side ? rec_node : lig_node) + (b * 512 + n) * 128;
    const float* edge = (side ? rec_edge : lig_edge) + (b * 512 + n) * 1024;

    __shared__ float s_node[128];
    __shared__ float s_edge[1024];
    __shared__ float s_out[128];

    const int tid = threadIdx.x;
    s_node[tid] = node[tid];
    ((float4*)s_edge)[tid]       = ((const float4*)edge)[tid];
    ((float4*)s_edge)[tid + 128] = ((const float4*)edge)[tid + 128];
    __syncthreads();

    const int o = tid;

    // hn[o] = sum_d WN[o][d]*node[d]  (4 chains via float4 components)
    float4 h4 = make_float4(0.f, 0.f, 0.f, 0.f);
    const float4* wn4 = (const float4*)WN4 + o;      // row stride 128 f4
    const float4* sn4 = (const float4*)s_node;
    #pragma unroll
    for (int d4 = 0; d4 < 32; ++d4) {
        const float4 w = wn4[d4 * 128];
        const float4 x = sn4[d4];                    // LDS broadcast b128
        h4.x = fmaf(w.x, x.x, h4.x);
        h4.y = fmaf(w.y, x.y, h4.y);
        h4.z = fmaf(w.z, x.z, h4.z);
        h4.w = fmaf(w.w, x.w, h4.w);
    }
    const float base = (h4.x + h4.y) + (h4.z + h4.w) + bN[o] + bE[o];

    // he[k][o]: 16 independent accumulators
    float acc[16];
    #pragma unroll
    for (int k = 0; k < 16; ++k) acc[k] = 0.f;
    const float4* we4 = (const float4*)WE4 + o;      // row stride 128 f4
    const float4* se4 = (const float4*)s_edge;
    #pragma unroll 4
    for (int e4 = 0; e4 < 16; ++e4) {
        const float4 w = we4[e4 * 128];
        #pragma unroll
        for (int k = 0; k < 16; ++k) {
            const float4 s = se4[k * 16 + e4];       // uniform addr broadcast
            acc[k] = fmaf(w.x, s.x, fmaf(w.y, s.y,
                     fmaf(w.z, s.z, fmaf(w.w, s.w, acc[k]))));
        }
    }

    // sum_k tanh(base + acc[k]);  tanh(x) = 1 - 2/(exp(2x)+1)  (exact limits)
    float ssum = 0.f;
    #pragma unroll
    for (int k = 0; k < 16; ++k) {
        const float ex = __expf(2.f * (base + acc[k]));
        ssum += 1.f - 2.f * __builtin_amdgcn_rcpf(ex + 1.f);
    }
    s_out[o] = s_node[o] + ssum * 0.0625f;
    __syncthreads();

    // projection: 32 outputs; coalesced WpT4 reads
    if (tid < 32) {
        const int c = side * 32 + tid;
        const float4* wp4 = (const float4*)WpT4 + c; // row stride 64 f4
        const float4* so4 = (const float4*)s_out;
        float4 a4 = make_float4(0.f, 0.f, 0.f, 0.f);
        #pragma unroll
        for (int d4 = 0; d4 < 32; ++d4) {
            const float4 w = wp4[d4 * 64];
            const float4 x = so4[d4];
            a4.x = fmaf(w.x, x.x, a4.x);
            a4.y = fmaf(w.y, x.y, a4.y);
            a4.z = fmaf(w.z, x.z, a4.z);
            a4.w = fmaf(w.w, x.w, a4.w);
        }
        const float vv = (a4.x + a4.y) + (a4.z + a4.w) + (side ? bp[tid] : 0.f);
        (side ? prb : pl)[(b * 512 + n) * 32 + tid] = vv;
    }
}

// u[c][b][l][co] / v[c][b][r][co]: 1D separable conv1 factors.
__global__ __launch_bounds__(256) void uv_kernel(
    const float* __restrict__ pl, const float* __restrict__ prb,
    const float* __restrict__ WA, const float* __restrict__ WB,
    const float* __restrict__ bc1,
    float* __restrict__ u, float* __restrict__ v)
{
    const int idx = blockIdx.x * 256 + threadIdx.x;   // 512 blocks * 256
    const int uv = idx >> 16;          // 0 = u (from pl), 1 = v (from prb)
    const int b  = (idx >> 14) & 3;
    const int l  = (idx >> 5) & 511;
    const int co = idx & 31;

    const float* p = (uv ? prb : pl) + (b * 512) * 32;
    const float* W = (uv ? WB : WA);
    float acc0 = uv ? 0.f : bc1[co];
    float acc1 = acc0, acc2 = acc0;
    #pragma unroll
    for (int d = 0; d < 3; ++d) {
        const int ln = l + d - 1;
        if (ln < 0 || ln >= 512) continue;
        const float* pv = p + ln * 32;
        const float* w0 = W + ((0 * 3 + d) * 32) * 32 + co;
        const float* w1 = W + ((1 * 3 + d) * 32) * 32 + co;
        const float* w2 = W + ((2 * 3 + d) * 32) * 32 + co;
        #pragma unroll
        for (int ci = 0; ci < 32; ++ci) {
            const float x = pv[ci];
            acc0 = fmaf(w0[ci * 32], x, acc0);
            acc1 = fmaf(w1[ci * 32], x, acc1);
            acc2 = fmaf(w2[ci * 32], x, acc2);
        }
    }
    float* dst = uv ? v : u;
    const int base = (b * 512 + l) * 32 + co;
    dst[0 * 65536 + base] = acc0;   // plane stride 4*512*32
    dst[1 * 65536 + base] = acc1;
    dst[2 * 65536 + base] = acc2;
}

// One block per 16x16 output tile. Phase B: y1=relu(u+v) in bf16 LDS.
// Phase C: conv2 via mfma_f32_16x16x32_bf16, fused relu/conv3/sigmoid.
__global__ __launch_bounds__(256) void conv_fused_kernel(
    const float* __restrict__ u, const float* __restrict__ v,
    const unsigned short* __restrict__ W2F,
    const float* __restrict__ bc2,
    const float* __restrict__ Wc3, const float* __restrict__ bc3,
    float* __restrict__ out)
{
    const int tc = blockIdx.x, tr = blockIdx.y, b = blockIdx.z;
    const int l0 = tr * 16, r0 = tc * 16;
    __shared__ unsigned short sY1[324 * 40];   // bf16, row stride 40 (80 B)
    const int tid = threadIdx.x;

    // Phase B: y1 halo in bf16
    for (int p = tid; p < 324; p += 256) {
        const int i = p / 18, j = p - i * 18;
        const int l = l0 + i - 1, r = r0 + j - 1;
        uint4 q0 = make_uint4(0u, 0u, 0u, 0u), q1 = q0, q2 = q0, q3 = q0;
        if ((l >= 0) & (l < 512) & (r >= 0) & (r < 512)) {
            const int cr = (r == 0) ? 0 : (r == 511) ? 2 : 1;
            const int cl = (l == 0) ? 0 : (l == 511) ? 2 : 1;
            const float4* up = (const float4*)&u[((cr * 4 + b) * 512 + l) * 32];
            const float4* vp = (const float4*)&v[((cl * 4 + b) * 512 + r) * 32];
            float y[32];
            #pragma unroll
            for (int c4 = 0; c4 < 8; ++c4) {
                const float4 a = up[c4], q = vp[c4];
                y[c4 * 4 + 0] = fmaxf(a.x + q.x, 0.f);
                y[c4 * 4 + 1] = fmaxf(a.y + q.y, 0.f);
                y[c4 * 4 + 2] = fmaxf(a.z + q.z, 0.f);
                y[c4 * 4 + 3] = fmaxf(a.w + q.w, 0.f);
            }
            q0 = make_uint4(pack_bf16_2(y[0], y[1]),  pack_bf16_2(y[2], y[3]),
                            pack_bf16_2(y[4], y[5]),  pack_bf16_2(y[6], y[7]));
            q1 = make_uint4(pack_bf16_2(y[8], y[9]),  pack_bf16_2(y[10], y[11]),
                            pack_bf16_2(y[12], y[13]), pack_bf16_2(y[14], y[15]));
            q2 = make_uint4(pack_bf16_2(y[16], y[17]), pack_bf16_2(y[18], y[19]),
                            pack_bf16_2(y[20], y[21]), pack_bf16_2(y[22], y[23]));
            q3 = make_uint4(pack_bf16_2(y[24], y[25]), pack_bf16_2(y[26], y[27]),
                            pack_bf16_2(y[28], y[29]), pack_bf16_2(y[30], y[31]));
        }
        uint4* dst = (uint4*)&sY1[p * 40];
        dst[0] = q0; dst[1] = q1; dst[2] = q2; dst[3] = q3;
    }

    // Preload conv2 B-fragments (global, L2-resident) + per-lane epilogue consts
    const int lane = tid & 63;
    const int wv   = tid >> 6;            // wave 0..3
    const int m    = lane & 15;           // A row (tx), C/D col (co within half)
    const int kc   = lane >> 4;           // k-chunk; C/D row group
    short8v bf[18];
    #pragma unroll
    for (int f = 0; f < 18; ++f)
        bf[f] = *(const short8v*)&W2F[(f * 64 + lane) * 8];
    const float bc2_0 = bc2[m],      bc2_1 = bc2[m + 16];
    const float wc3_0 = Wc3[m],      wc3_1 = Wc3[m + 16];
    const float bc3v  = bc3[0];

    __syncthreads();

    // Phase C: each wave handles 4 output rows ty = wv*4 + i
    #pragma unroll 1
    for (int i = 0; i < 4; ++i) {
        const int ty = wv * 4 + i;
        f32x4 acc0 = {0.f, 0.f, 0.f, 0.f};
        f32x4 acc1 = {0.f, 0.f, 0.f, 0.f};
        #pragma unroll
        for (int dy = 0; dy < 3; ++dy) {
            #pragma unroll
            for (int dx = 0; dx < 3; ++dx) {
                const short8v a = *(const short8v*)
                    &sY1[((ty + dy) * 18 + m + dx) * 40 + kc * 8];
                const int t = dy * 3 + dx;
                acc0 = __builtin_amdgcn_mfma_f32_16x16x32_bf16(a, bf[t * 2 + 0], acc0, 0, 0, 0);
                acc1 = __builtin_amdgcn_mfma_f32_16x16x32_bf16(a, bf[t * 2 + 1], acc1, 0, 0, 0);
            }
        }
        // Epilogue: relu + conv3 dot over co (16-lane butterfly), sigmoid, store
        #pragma unroll
        for (int reg = 0; reg < 4; ++reg) {
            float vlt = fmaxf(acc0[reg] + bc2_0, 0.f) * wc3_0
                      + fmaxf(acc1[reg] + bc2_1, 0.f) * wc3_1;
            #pragma unroll
            for (int s = 1; s < 16; s <<= 1)
                vlt += __shfl_xor(vlt, s, 64);
            if (m == reg) {
                const int tx = kc * 4 + reg;
                const float sig = 1.f / (1.f + expf(-(vlt + bc3v)));
                out[(b * 512 + l0 + ty) * 512 + (r0 + tx)] = sig;
            }
        }
    }
}

extern "C" void kernel_launch(void* const* d_in, const int* in_sizes, int n_in,
                              void* d_out, int out_size, void* d_ws, size_t ws_size,
                              hipStream_t stream) {
    const float* lig_node = (const float*)d_in[0];
    const float* lig_edge = (const float*)d_in[1];
    const float* rec_node = (const float*)d_in[2];
    const float* rec_edge = (const float*)d_in[3];
    const float* WN  = (const float*)d_in[4];
    const float* bN  = (const float*)d_in[5];
    const float* WE  = (const float*)d_in[6];
    const float* bE  = (const float*)d_in[7];
    const float* Wp  = (const float*)d_in[8];
    const float* bp  = (const float*)d_in[9];
    const float* Wc1 = (const float*)d_in[10];
    const float* bc1 = (const float*)d_in[11];
    const float* Wc2 = (const float*)d_in[12];
    const float* bc2 = (const float*)d_in[13];
    const float* Wc3 = (const float*)d_in[14];
    const float* bc3 = (const float*)d_in[15];
    float* out = (float*)d_out;

    float* ws  = (float*)d_ws;
    float* pl   = ws;
    float* prb  = ws + 65536;
    float* WA   = ws + 131072;
    float* WB   = ws + 140288;
    unsigned short* W2F = (unsigned short*)(ws + 149504);
    float* u    = ws + 158720;
    float* v    = ws + 355328;
    float* WN4  = ws + 551936;
    float* WE4  = ws + 568320;
    float* WpT4 = ws + 576512;

    hipLaunchKernelGGL(prep_weights, dim3(64), dim3(256), 0, stream,
                       Wc1, Wc2, WN, WE, Wp, WA, WB, W2F, WN4, WE4, WpT4);
    hipLaunchKernelGGL(gnn_proj_kernel, dim3(4096), dim3(128), 0, stream,
                       lig_node, lig_edge, rec_node, rec_edge,
                       WN4, bN, WE4, bE, WpT4, bp, pl, prb);
    hipLaunchKernelGGL(uv_kernel, dim3(512), dim3(256), 0, stream,
                       pl, prb, WA, WB, bc1, u, v);
    hipLaunchKernelGGL(conv_fused_kernel, dim3(32, 32, 4), dim3(256), 0, stream,
                       u, v, W2F, bc2, Wc3, bc3, out);
}

// Round 12
// 186.727 us; speedup vs baseline: 1.2458x; 1.2458x over previous
//
#include <hip/hip_runtime.h>
#include <hip/hip_bf16.h>
#include <math.h>

// ---------------------------------------------------------------------------
// ProteinInterfacePrediction
// B=4, L=R=512, K=16, DN=128, DE=64, HOPI=32, CNNC=32
//
// conv1 separability: P[l,r,:] = pA[l,:]+pB[r,:], conv1 linear =>
//   y1(pre-relu)[l,r,co] = u[cr(r)][b][l][co] + v[cl(l)][b][r][co]
// conv2 on the bf16 MFMA pipe (16x16x32), fused relu/conv3/sigmoid epilogue.
// GNN: lane-transposed e4-packed weights (coalesced float4 fetches);
// 16 independent he accumulators; closed-form tanh.
// R11 lesson: unroll-4 on e4 + acc[16] blew VGPR to 156 -> 10% occupancy.
// Fix: __launch_bounds__(128,4) caps 128 VGPR; unroll 1 on e4 loop.
//
// ws layout (floats):
//   pl  : [4][512][32]   @ 0        (65536)
//   prb : [4][512][32]   @ 65536    (65536)
//   WA  : [3][3][32][32] @ 131072   (9216)   kx-summed conv1 w, [c][ky][ci][co]
//   WB  : [3][3][32][32] @ 140288   (9216)   ky-summed conv1 w, [c][kx][ci][co]
//   W2F : bf16[18][64][8]@ 149504   (4608 f) conv2 B-fragments, per-lane packed
//   u   : [3][4][512][32]@ 158720   (196608) plane stride 65536
//   v   : [3][4][512][32]@ 355328   (196608) plane stride 65536
//   WN4 : [32][128][4]   @ 551936   (16384)  WN4[d4][o][j] = WN[o][d4*4+j]
//   WE4 : [16][128][4]   @ 568320   (8192)   WE4[e4][o][j] = WE[o][e4*4+j]
//   WpT4: [32][64][4]    @ 576512   (8192)   WpT4[d4][s*32+po][j] = Wp[po][s*128+d4*4+j]
// ---------------------------------------------------------------------------

typedef __attribute__((ext_vector_type(8))) short short8v;   // 8 x bf16
typedef __attribute__((ext_vector_type(4))) float f32x4;

__device__ __forceinline__ unsigned pack_bf16_2(float x, float y) {
    __hip_bfloat16 hx = __float2bfloat16(x);
    __hip_bfloat16 hy = __float2bfloat16(y);
    unsigned short ux = *(unsigned short*)&hx;
    unsigned short uy = *(unsigned short*)&hy;
    return (unsigned)ux | ((unsigned)uy << 16);
}

__global__ __launch_bounds__(256) void prep_weights(
    const float* __restrict__ Wc1, const float* __restrict__ Wc2,
    const float* __restrict__ WN, const float* __restrict__ WE,
    const float* __restrict__ Wp,
    float* __restrict__ WA, float* __restrict__ WB,
    unsigned short* __restrict__ W2F,
    float* __restrict__ WN4, float* __restrict__ WE4,
    float* __restrict__ WpT4)
{
    const int t = blockIdx.x * 256 + threadIdx.x;   // 64 blocks -> 16384

    if (t < 9216) {
        // conv2 B-fragment packing: W2F[f][lane][j], f = tap*2 + half
        const int f    = t >> 9;          // 0..17
        const int lane = (t >> 3) & 63;
        const int j    = t & 7;
        const int tap  = f >> 1;
        const int h    = f & 1;
        const int co   = h * 16 + (lane & 15);
        const int ci   = (lane >> 4) * 8 + j;
        const float w  = Wc2[(co * 32 + ci) * 9 + tap];
        __hip_bfloat16 hb = __float2bfloat16(w);
        W2F[t] = *(unsigned short*)&hb;

        // conv1 separable tap-sum weights
        const int tap1 = t >> 10;         // 0..8
        const int ci1  = (t >> 5) & 31;
        const int co1  = t & 31;
        if (tap1 < 3) {
            const int k = tap1;
            const float* w1 = Wc1 + (co1 * 32 + ci1) * 9;
            float w0 = w1[k * 3 + 0], wq = w1[k * 3 + 1], w2 = w1[k * 3 + 2];
            WA[((0 * 3 + k) * 32 + ci1) * 32 + co1] = wq + w2;        // r == 0
            WA[((1 * 3 + k) * 32 + ci1) * 32 + co1] = w0 + wq + w2;   // interior
            WA[((2 * 3 + k) * 32 + ci1) * 32 + co1] = w0 + wq;        // r == 511
            float q0 = w1[0 * 3 + k], q1 = w1[1 * 3 + k], q2 = w1[2 * 3 + k];
            WB[((0 * 3 + k) * 32 + ci1) * 32 + co1] = q1 + q2;        // l == 0
            WB[((1 * 3 + k) * 32 + ci1) * 32 + co1] = q0 + q1 + q2;   // interior
            WB[((2 * 3 + k) * 32 + ci1) * 32 + co1] = q0 + q1;        // l == 511
        }
    }
    if (t < 16384) {   // WN4[d4][o][j] = WN[o][d4*4+j]
        const int d4 = t >> 9, o = (t >> 2) & 127, j = t & 3;
        WN4[t] = WN[o * 128 + d4 * 4 + j];
    }
    if (t < 8192) {    // WE4[e4][o][j] = WE[o][e4*4+j]
        const int e4 = t >> 9, o = (t >> 2) & 127, j = t & 3;
        WE4[t] = WE[o * 64 + e4 * 4 + j];
    }
    if (t < 8192) {    // WpT4[d4][s*32+po][j] = Wp[po][s*128+d4*4+j]
        const int d4 = t >> 8, c = (t >> 2) & 63, j = t & 3;
        const int s = c >> 5, po = c & 31;
        WpT4[t] = Wp[po * 256 + s * 128 + d4 * 4 + j];
    }
}

// One block per (side, b, n). 128 threads. Coalesced f4 weight fetches.
// __launch_bounds__(128, 4): cap 128 VGPR -> 4 waves/SIMD (R11: 156 VGPR
// at default bounds collapsed occupancy to 10%).
__global__ __launch_bounds__(128, 4) void gnn_proj_kernel(
    const float* __restrict__ lig_node, const float* __restrict__ lig_edge,
    const float* __restrict__ rec_node, const float* __restrict__ rec_edge,
    const float* __restrict__ WN4, const float* __restrict__ bN,
    const float* __restrict__ WE4, const float* __restrict__ bE,
    const float* __restrict__ WpT4, const float* __restrict__ bp,
    float* __restrict__ pl, float* __restrict__ prb)
{
    const int blk  = blockIdx.x;          // 0..4095
    const int side = blk >> 11;           // 0 = ligand, 1 = receptor
    const int b    = (blk >> 9) & 3;
    const int n    = blk & 511;
    const float* node = (side ? rec_node : lig_node) + (b * 512 + n) * 128;
    const float* edge = (side ? rec_edge : lig_edge) + (b * 512 + n) * 1024;

    __shared__ float s_node[128];
    __shared__ float s_edge[1024];
    __shared__ float s_out[128];

    const int tid = threadIdx.x;
    s_node[tid] = node[tid];
    ((float4*)s_edge)[tid]       = ((const float4*)edge)[tid];
    ((float4*)s_edge)[tid + 128] = ((const float4*)edge)[tid + 128];
    __syncthreads();

    const int o = tid;

    // hn[o] = sum_d WN[o][d]*node[d]  (4 chains via float4 components)
    float4 h4 = make_float4(0.f, 0.f, 0.f, 0.f);
    const float4* wn4 = (const float4*)WN4 + o;      // row stride 128 f4
    const float4* sn4 = (const float4*)s_node;
    #pragma unroll 1
    for (int d4 = 0; d4 < 32; ++d4) {
        const float4 w = wn4[d4 * 128];
        const float4 x = sn4[d4];                    // LDS broadcast b128
        h4.x = fmaf(w.x, x.x, h4.x);
        h4.y = fmaf(w.y, x.y, h4.y);
        h4.z = fmaf(w.z, x.z, h4.z);
        h4.w = fmaf(w.w, x.w, h4.w);
    }
    const float base = (h4.x + h4.y) + (h4.z + h4.w) + bN[o] + bE[o];

    // he[k][o]: 16 independent accumulators; unroll 1 keeps live set small
    float acc[16];
    #pragma unroll
    for (int k = 0; k < 16; ++k) acc[k] = 0.f;
    const float4* we4 = (const float4*)WE4 + o;      // row stride 128 f4
    const float4* se4 = (const float4*)s_edge;
    #pragma unroll 1
    for (int e4 = 0; e4 < 16; ++e4) {
        const float4 w = we4[e4 * 128];
        #pragma unroll
        for (int k = 0; k < 16; ++k) {
            const float4 s = se4[k * 16 + e4];       // uniform addr broadcast
            acc[k] = fmaf(w.x, s.x, fmaf(w.y, s.y,
                     fmaf(w.z, s.z, fmaf(w.w, s.w, acc[k]))));
        }
    }

    // sum_k tanh(base + acc[k]);  tanh(x) = 1 - 2/(exp(2x)+1)  (exact limits)
    float ssum = 0.f;
    #pragma unroll
    for (int k = 0; k < 16; ++k) {
        const float ex = __expf(2.f * (base + acc[k]));
        ssum += 1.f - 2.f * __builtin_amdgcn_rcpf(ex + 1.f);
    }
    s_out[o] = s_node[o] + ssum * 0.0625f;
    __syncthreads();

    // projection: 32 outputs; coalesced WpT4 reads
    if (tid < 32) {
        const int c = side * 32 + tid;
        const float4* wp4 = (const float4*)WpT4 + c; // row stride 64 f4
        const float4* so4 = (const float4*)s_out;
        float4 a4 = make_float4(0.f, 0.f, 0.f, 0.f);
        #pragma unroll 1
        for (int d4 = 0; d4 < 32; ++d4) {
            const float4 w = wp4[d4 * 64];
            const float4 x = so4[d4];
            a4.x = fmaf(w.x, x.x, a4.x);
            a4.y = fmaf(w.y, x.y, a4.y);
            a4.z = fmaf(w.z, x.z, a4.z);
            a4.w = fmaf(w.w, x.w, a4.w);
        }
        const float vv = (a4.x + a4.y) + (a4.z + a4.w) + (side ? bp[tid] : 0.f);
        (side ? prb : pl)[(b * 512 + n) * 32 + tid] = vv;
    }
}

// u[c][b][l][co] / v[c][b][r][co]: 1D separable conv1 factors.
__global__ __launch_bounds__(256) void uv_kernel(
    const float* __restrict__ pl, const float* __restrict__ prb,
    const float* __restrict__ WA, const float* __restrict__ WB,
    const float* __restrict__ bc1,
    float* __restrict__ u, float* __restrict__ v)
{
    const int idx = blockIdx.x * 256 + threadIdx.x;   // 512 blocks * 256
    const int uv = idx >> 16;          // 0 = u (from pl), 1 = v (from prb)
    const int b  = (idx >> 14) & 3;
    const int l  = (idx >> 5) & 511;
    const int co = idx & 31;

    const float* p = (uv ? prb : pl) + (b * 512) * 32;
    const float* W = (uv ? WB : WA);
    float acc0 = uv ? 0.f : bc1[co];
    float acc1 = acc0, acc2 = acc0;
    #pragma unroll
    for (int d = 0; d < 3; ++d) {
        const int ln = l + d - 1;
        if (ln < 0 || ln >= 512) continue;
        const float* pv = p + ln * 32;
        const float* w0 = W + ((0 * 3 + d) * 32) * 32 + co;
        const float* w1 = W + ((1 * 3 + d) * 32) * 32 + co;
        const float* w2 = W + ((2 * 3 + d) * 32) * 32 + co;
        #pragma unroll
        for (int ci = 0; ci < 32; ++ci) {
            const float x = pv[ci];
            acc0 = fmaf(w0[ci * 32], x, acc0);
            acc1 = fmaf(w1[ci * 32], x, acc1);
            acc2 = fmaf(w2[ci * 32], x, acc2);
        }
    }
    float* dst = uv ? v : u;
    const int base = (b * 512 + l) * 32 + co;
    dst[0 * 65536 + base] = acc0;   // plane stride 4*512*32
    dst[1 * 65536 + base] = acc1;
    dst[2 * 65536 + base] = acc2;
}

// One block per 16x16 output tile. Phase B: y1=relu(u+v) in bf16 LDS.
// Phase C: conv2 via mfma_f32_16x16x32_bf16, fused relu/conv3/sigmoid.
__global__ __launch_bounds__(256) void conv_fused_kernel(
    const float* __restrict__ u, const float* __restrict__ v,
    const unsigned short* __restrict__ W2F,
    const float* __restrict__ bc2,
    const float* __restrict__ Wc3, const float* __restrict__ bc3,
    float* __restrict__ out)
{
    const int tc = blockIdx.x, tr = blockIdx.y, b = blockIdx.z;
    const int l0 = tr * 16, r0 = tc * 16;
    __shared__ unsigned short sY1[324 * 40];   // bf16, row stride 40 (80 B)
    const int tid = threadIdx.x;

    // Phase B: y1 halo in bf16
    for (int p = tid; p < 324; p += 256) {
        const int i = p / 18, j = p - i * 18;
        const int l = l0 + i - 1, r = r0 + j - 1;
        uint4 q0 = make_uint4(0u, 0u, 0u, 0u), q1 = q0, q2 = q0, q3 = q0;
        if ((l >= 0) & (l < 512) & (r >= 0) & (r < 512)) {
            const int cr = (r == 0) ? 0 : (r == 511) ? 2 : 1;
            const int cl = (l == 0) ? 0 : (l == 511) ? 2 : 1;
            const float4* up = (const float4*)&u[((cr * 4 + b) * 512 + l) * 32];
            const float4* vp = (const float4*)&v[((cl * 4 + b) * 512 + r) * 32];
            float y[32];
            #pragma unroll
            for (int c4 = 0; c4 < 8; ++c4) {
                const float4 a = up[c4], q = vp[c4];
                y[c4 * 4 + 0] = fmaxf(a.x + q.x, 0.f);
                y[c4 * 4 + 1] = fmaxf(a.y + q.y, 0.f);
                y[c4 * 4 + 2] = fmaxf(a.z + q.z, 0.f);
                y[c4 * 4 + 3] = fmaxf(a.w + q.w, 0.f);
            }
            q0 = make_uint4(pack_bf16_2(y[0], y[1]),  pack_bf16_2(y[2], y[3]),
                            pack_bf16_2(y[4], y[5]),  pack_bf16_2(y[6], y[7]));
            q1 = make_uint4(pack_bf16_2(y[8], y[9]),  pack_bf16_2(y[10], y[11]),
                            pack_bf16_2(y[12], y[13]), pack_bf16_2(y[14], y[15]));
            q2 = make_uint4(pack_bf16_2(y[16], y[17]), pack_bf16_2(y[18], y[19]),
                            pack_bf16_2(y[20], y[21]), pack_bf16_2(y[22], y[23]));
            q3 = make_uint4(pack_bf16_2(y[24], y[25]), pack_bf16_2(y[26], y[27]),
                            pack_bf16_2(y[28], y[29]), pack_bf16_2(y[30], y[31]));
        }
        uint4* dst = (uint4*)&sY1[p * 40];
        dst[0] = q0; dst[1] = q1; dst[2] = q2; dst[3] = q3;
    }

    // Preload conv2 B-fragments (global, L2-resident) + per-lane epilogue consts
    const int lane = tid & 63;
    const int wv   = tid >> 6;            // wave 0..3
    const int m    = lane & 15;           // A row (tx), C/D col (co within half)
    const int kc   = lane >> 4;           // k-chunk; C/D row group
    short8v bf[18];
    #pragma unroll
    for (int f = 0; f < 18; ++f)
        bf[f] = *(const short8v*)&W2F[(f * 64 + lane) * 8];
    const float bc2_0 = bc2[m],      bc2_1 = bc2[m + 16];
    const float wc3_0 = Wc3[m],      wc3_1 = Wc3[m + 16];
    const float bc3v  = bc3[0];

    __syncthreads();

    // Phase C: each wave handles 4 output rows ty = wv*4 + i
    #pragma unroll 1
    for (int i = 0; i < 4; ++i) {
        const int ty = wv * 4 + i;
        f32x4 acc0 = {0.f, 0.f, 0.f, 0.f};
        f32x4 acc1 = {0.f, 0.f, 0.f, 0.f};
        #pragma unroll
        for (int dy = 0; dy < 3; ++dy) {
            #pragma unroll
            for (int dx = 0; dx < 3; ++dx) {
                const short8v a = *(const short8v*)
                    &sY1[((ty + dy) * 18 + m + dx) * 40 + kc * 8];
                const int t = dy * 3 + dx;
                acc0 = __builtin_amdgcn_mfma_f32_16x16x32_bf16(a, bf[t * 2 + 0], acc0, 0, 0, 0);
                acc1 = __builtin_amdgcn_mfma_f32_16x16x32_bf16(a, bf[t * 2 + 1], acc1, 0, 0, 0);
            }
        }
        // Epilogue: relu + conv3 dot over co (16-lane butterfly), sigmoid, store
        #pragma unroll
        for (int reg = 0; reg < 4; ++reg) {
            float vlt = fmaxf(acc0[reg] + bc2_0, 0.f) * wc3_0
                      + fmaxf(acc1[reg] + bc2_1, 0.f) * wc3_1;
            #pragma unroll
            for (int s = 1; s < 16; s <<= 1)
                vlt += __shfl_xor(vlt, s, 64);
            if (m == reg) {
                const int tx = kc * 4 + reg;
                const float sig = 1.f / (1.f + expf(-(vlt + bc3v)));
                out[(b * 512 + l0 + ty) * 512 + (r0 + tx)] = sig;
            }
        }
    }
}

extern "C" void kernel_launch(void* const* d_in, const int* in_sizes, int n_in,
                              void* d_out, int out_size, void* d_ws, size_t ws_size,
                              hipStream_t stream) {
    const float* lig_node = (const float*)d_in[0];
    const float* lig_edge = (const float*)d_in[1];
    const float* rec_node = (const float*)d_in[2];
    const float* rec_edge = (const float*)d_in[3];
    const float* WN  = (const float*)d_in[4];
    const float* bN  = (const float*)d_in[5];
    const float* WE  = (const float*)d_in[6];
    const float* bE  = (const float*)d_in[7];
    const float* Wp  = (const float*)d_in[8];
    const float* bp  = (const float*)d_in[9];
    const float* Wc1 = (const float*)d_in[10];
    const float* bc1 = (const float*)d_in[11];
    const float* Wc2 = (const float*)d_in[12];
    const float* bc2 = (const float*)d_in[13];
    const float* Wc3 = (const float*)d_in[14];
    const float* bc3 = (const float*)d_in[15];
    float* out = (float*)d_out;

    float* ws  = (float*)d_ws;
    float* pl   = ws;
    float* prb  = ws + 65536;
    float* WA   = ws + 131072;
    float* WB   = ws + 140288;
    unsigned short* W2F = (unsigned short*)(ws + 149504);
    float* u    = ws + 158720;
    float* v    = ws + 355328;
    float* WN4  = ws + 551936;
    float* WE4  = ws + 568320;
    float* WpT4 = ws + 576512;

    hipLaunchKernelGGL(prep_weights, dim3(64), dim3(256), 0, stream,
                       Wc1, Wc2, WN, WE, Wp, WA, WB, W2F, WN4, WE4, WpT4);
    hipLaunchKernelGGL(gnn_proj_kernel, dim3(4096), dim3(128), 0, stream,
                       lig_node, lig_edge, rec_node, rec_edge,
                       WN4, bN, WE4, bE, WpT4, bp, pl, prb);
    hipLaunchKernelGGL(uv_kernel, dim3(512), dim3(256), 0, stream,
                       pl, prb, WA, WB, bc1, u, v);
    hipLaunchKernelGGL(conv_fused_kernel, dim3(32, 32, 4), dim3(256), 0, stream,
                       u, v, W2F, bc2, Wc3, bc3, out);
}